// Round 11
// baseline (278.671 us; speedup 1.0000x reference)
//
#include <hip/hip_runtime.h>

#define BATCH 16
#define NQ 2048
#define NK 2048

typedef short s16x8 __attribute__((ext_vector_type(8)));
typedef __bf16 bf16x8 __attribute__((ext_vector_type(8)));
typedef float f32x16 __attribute__((ext_vector_type(16)));
typedef float f32x4 __attribute__((ext_vector_type(4)));
typedef int i32x4 __attribute__((ext_vector_type(4)));

static __device__ __forceinline__ unsigned short f2bf(float f) {
  unsigned u = __builtin_bit_cast(unsigned, f);
  u += 0x7FFFu + ((u >> 16) & 1u);   // round-to-nearest-even
  return (unsigned short)(u >> 16);
}

static __device__ __forceinline__ f32x16 mfma32(s16x8 a, s16x8 b, f32x16 c) {
  return __builtin_amdgcn_mfma_f32_32x32x16_bf16(
      __builtin_bit_cast(bf16x8, a), __builtin_bit_cast(bf16x8, b), c, 0, 0, 0);
}

static __device__ __forceinline__ f32x4 mfma16(s16x8 a, s16x8 b, f32x4 c) {
  return __builtin_amdgcn_mfma_f32_16x16x32_bf16(
      __builtin_bit_cast(bf16x8, a), __builtin_bit_cast(bf16x8, b), c, 0, 0, 0);
}

// p = exp(10*tanh(s) - 10) = exp2(-28.8539.../(e^(2s)+1)), e^(2s)=exp2(2.88539*s)
static __device__ __forceinline__ float score_p(float s) {
  float u = __builtin_amdgcn_exp2f(s * 2.885390081777927f);
  return __builtin_amdgcn_exp2f(-28.853900817779268f * __builtin_amdgcn_rcpf(u + 1.0f));
}

// WT[n][k] = W[k][n] * scale, cast to bf16.  Grid: (256, 2) x 256 thr.
__global__ void prep_wt(const float* __restrict__ Wk, unsigned short* __restrict__ WkT,
                        const float* __restrict__ Wq, unsigned short* __restrict__ WqT) {
  const float* W = blockIdx.y ? Wq : Wk;
  unsigned short* WT = blockIdx.y ? WqT : WkT;
  float scale = blockIdx.y ? 0.0625f : 1.0f;   // fold 1/sqrt(256) into Wq
  int idx = blockIdx.x * 256 + threadIdx.x;
  int n = idx >> 8, k = idx & 255;
  WT[n * 256 + k] = f2bf(W[k * 256 + n] * scale);
}

// Projection; output packed in 16x16x32-MFMA fragment order for 16-row tiles:
//   Yf[((t16*8 + kk)*64 + lane)*8 + j] = Y[row = t16*16 + (lane&15)]
//                                         [e  = kk*32 + (lane>>4)*8 + j]
__global__ __launch_bounds__(256, 2) void proj_kernel(
    const float* __restrict__ Xk, const unsigned short* __restrict__ WkT,
    unsigned short* __restrict__ Yk,
    const float* __restrict__ Xq, const unsigned short* __restrict__ WqT,
    unsigned short* __restrict__ Yq) {
  const float* X;
  const unsigned short* WT;
  unsigned short* Y;
  if (blockIdx.y == 0) { X = Xk; WT = WkT; Y = Yk; }
  else                 { X = Xq; WT = WqT; Y = Yq; }

  int tid = threadIdx.x;
  int wave = tid >> 6, lane = tid & 63;
  int l31 = lane & 31, kh = lane >> 5;
  int r0 = blockIdx.x * 128 + wave * 32;

  const float* xp = X + (size_t)(r0 + l31) * 256 + kh * 8;

  f32x16 acc[8];
#pragma unroll
  for (int ct = 0; ct < 8; ++ct)
#pragma unroll
    for (int i = 0; i < 16; ++i) acc[ct][i] = 0.0f;

#pragma unroll
  for (int kk = 0; kk < 16; ++kk) {
    f32x4 a0 = *(const f32x4*)(xp + kk * 16);
    f32x4 a1 = *(const f32x4*)(xp + kk * 16 + 4);
    s16x8 af;
#pragma unroll
    for (int j = 0; j < 4; ++j) {
      af[j]     = (short)f2bf(a0[j]);
      af[4 + j] = (short)f2bf(a1[j]);
    }
#pragma unroll
    for (int ct = 0; ct < 8; ++ct) {
      s16x8 bw = *(const s16x8*)(WT + (size_t)(ct * 32 + l31) * 256 + kk * 16 + kh * 8);
      acc[ct] = mfma32(af, bw, acc[ct]);
    }
  }

  // epilogue: scatter into 16-row-tile fragment order
  int kg2 = l31 >> 3, j = l31 & 7;
#pragma unroll
  for (int ct = 0; ct < 8; ++ct) {
#pragma unroll
    for (int r = 0; r < 16; ++r) {
      int rrow = (r & 3) + 8 * (r >> 2) + 4 * kh;
      int row = r0 + rrow;
      Y[((size_t)((row >> 4) * 8 + ct) * 64 + kg2 * 16 + (row & 15)) * 8 + j] =
          f2bf(acc[ct][r]);
    }
  }
}

// Fused adjacency-pack + scores + tanh-clip + mask + softmax, one-pass,
// all state in registers (P stash = 32 u32; no LDS P buffer).
// Grid: (128, 16) = 2048 blocks of 16 q-rows; 512 threads (8 waves), wave w
// owns cols [w*256, w*256+256) as 16 col-tiles of 16 (mfma 16x16x32).
// Adjacency: int4 nontemporal loads (1 KB/row/wave) + nibble + shfl-OR pack
// (no load->ballot serialization). Output: nontemporal stores. Streaming
// data bypasses L2 pollution so K panels (2 MB/XCD) stay L2-resident.
// XCD-aware remap: xcd = lin&7 owns batches {2*xcd, 2*xcd+1}.
__global__ __launch_bounds__(512, 2) void attn_kernel(
    const unsigned short* __restrict__ Kf, const unsigned short* __restrict__ Qf,
    const int* __restrict__ adj, float* __restrict__ out) {
  int lin = blockIdx.y * 128 + blockIdx.x;
  int b  = (lin & 7) * 2 + ((lin >> 3) & 1);
  int qt = lin >> 4;                 // 0..127: 16-row tile within batch
  int q0 = qt * 16;
  int tid = threadIdx.x;
  int wave = tid >> 6, lane = tid & 63;
  int l15 = lane & 15, kg = lane >> 4;
  int colbase = wave * 256;

  __shared__ unsigned lmask[8 * 144];   // mask words, row stride 9 (pad)
  __shared__ float wsum[8][16];
  __shared__ float rrecip[16];

  // Q fragments: global tile = b*128 + qt (8 KB, coalesced 1 KB loads)
  const unsigned short* qp = Qf + (size_t)(b * 128 + qt) * 8 * 512;
  s16x8 aq[8];
#pragma unroll
  for (int kk = 0; kk < 8; ++kk)
    aq[kk] = *(const s16x8*)(qp + ((size_t)kk * 64 + lane) * 8);

  // ---- wave-local adjacency pack: lane covers cols [lane*4, lane*4+4) ----
  const i32x4* ap4 =
      (const i32x4*)(adj + ((size_t)b * NQ + q0) * (size_t)NK + colbase) + lane;
  unsigned* lm = lmask + wave * 144;
#pragma unroll
  for (int half = 0; half < 2; ++half) {
    i32x4 av[8];
#pragma unroll
    for (int r8 = 0; r8 < 8; ++r8)
      av[r8] = __builtin_nontemporal_load(ap4 + (size_t)(half * 8 + r8) * (NK / 4));
#pragma unroll
    for (int r8 = 0; r8 < 8; ++r8) {
      i32x4 v = av[r8];
      unsigned nib = (v[0] != 0 ? 1u : 0u) | (v[1] != 0 ? 2u : 0u) |
                     (v[2] != 0 ? 4u : 0u) | (v[3] != 0 ? 8u : 0u);
      unsigned m = nib << ((lane & 7) * 4);
      m |= __shfl_xor(m, 1);
      m |= __shfl_xor(m, 2);
      m |= __shfl_xor(m, 4);   // all 8 lanes of group g=lane>>3 now hold word g
      if ((lane & 7) == 0) lm[(half * 8 + r8) * 9 + (lane >> 3)] = m;
    }
  }
  // no barrier: lmask slice is wave-local (lgkmcnt orders same-wave LDS)

  const unsigned short* kfb = Kf + (size_t)b * 128 * 8 * 512;

  float rsum[4] = {0.0f, 0.0f, 0.0f, 0.0f};
  unsigned pstl[16], psth[16];   // P bf16x2 stash, fully static indexing

#pragma unroll
  for (int ct = 0; ct < 16; ++ct) {
    f32x4 acc = {0.0f, 0.0f, 0.0f, 0.0f};
    const unsigned short* kpt = kfb + (size_t)(wave * 16 + ct) * 8 * 512;
#pragma unroll
    for (int kk = 0; kk < 8; ++kk) {
      s16x8 bk = *(const s16x8*)(kpt + ((size_t)kk * 64 + lane) * 8);
      acc = mfma16(aq[kk], bk, acc);
    }
    // D[row=kg*4+r][col=l15]; global col = colbase + ct*16 + l15
    unsigned shift = (unsigned)((ct & 1) * 16 + l15);
    float p[4];
#pragma unroll
    for (int r = 0; r < 4; ++r) {
      unsigned mw = lm[(kg * 4 + r) * 9 + (ct >> 1)];
      float e = score_p(acc[r]);
      p[r] = ((mw >> shift) & 1u) ? e : 0.0f;
      rsum[r] += p[r];
    }
    pstl[ct] = (unsigned)f2bf(p[0]) | ((unsigned)f2bf(p[1]) << 16);
    psth[ct] = (unsigned)f2bf(p[2]) | ((unsigned)f2bf(p[3]) << 16);
  }

  // col-reduce within each 16-lane quarter (rows disjoint across quarters)
#pragma unroll
  for (int r = 0; r < 4; ++r) {
    float v = rsum[r];
    v += __shfl_xor(v, 1);
    v += __shfl_xor(v, 2);
    v += __shfl_xor(v, 4);
    v += __shfl_xor(v, 8);
    rsum[r] = v;
  }
  if (l15 == 0) {
#pragma unroll
    for (int r = 0; r < 4; ++r) wsum[wave][kg * 4 + r] = rsum[r];
  }
  __syncthreads();
  if (tid < 16) {
    float s = 0.0f;
#pragma unroll
    for (int w = 0; w < 8; ++w) s += wsum[w][tid];
    rrecip[tid] = 1.0f / s;
  }
  __syncthreads();

  float rc[4];
#pragma unroll
  for (int r = 0; r < 4; ++r) rc[r] = rrecip[kg * 4 + r];

  // normalize from register stash, nontemporal store
  float* op = out + ((size_t)b * NQ + q0 + kg * 4) * (size_t)NK + colbase + l15;
#pragma unroll
  for (int ct = 0; ct < 16; ++ct) {
    float p0 = __builtin_bit_cast(float, pstl[ct] << 16);
    float p1 = __builtin_bit_cast(float, pstl[ct] & 0xffff0000u);
    float p2 = __builtin_bit_cast(float, psth[ct] << 16);
    float p3 = __builtin_bit_cast(float, psth[ct] & 0xffff0000u);
    __builtin_nontemporal_store(p0 * rc[0], op + (size_t)0 * NK + ct * 16);
    __builtin_nontemporal_store(p1 * rc[1], op + (size_t)1 * NK + ct * 16);
    __builtin_nontemporal_store(p2 * rc[2], op + (size_t)2 * NK + ct * 16);
    __builtin_nontemporal_store(p3 * rc[3], op + (size_t)3 * NK + ct * 16);
  }
}

extern "C" void kernel_launch(void* const* d_in, const int* in_sizes, int n_in,
                              void* d_out, int out_size, void* d_ws, size_t ws_size,
                              hipStream_t stream) {
  const float* k_in = (const float*)d_in[0];
  const float* q_in = (const float*)d_in[1];
  const int* adj    = (const int*)d_in[2];
  const float* Wk   = (const float*)d_in[3];
  const float* Wq   = (const float*)d_in[4];
  float* out = (float*)d_out;

  char* ws = (char*)d_ws;
  unsigned short* WkT = (unsigned short*)(ws);                           // 128 KB
  unsigned short* WqT = (unsigned short*)(ws + (1u << 17));              // 128 KB
  unsigned short* Kf  = (unsigned short*)(ws + (1u << 18));              // 16 MB
  unsigned short* Qf  = (unsigned short*)(ws + (1u << 18) + (1u << 24)); // 16 MB

  prep_wt<<<dim3(256, 2), 256, 0, stream>>>(Wk, WkT, Wq, WqT);

  proj_kernel<<<dim3(256, 2), 256, 0, stream>>>(k_in, WkT, Kf, q_in, WqT, Qf);

  attn_kernel<<<dim3(128, 16), 512, 0, stream>>>(Kf, Qf, adj, out);
}